// Round 1
// baseline (196.319 us; speedup 1.0000x reference)
//
#include <hip/hip_runtime.h>
#include <math.h>

// CoralLossV2: mean over (B, Km1) of
//   max(x,0) - x*[t > k] + log1p(exp(-|x|))  ==  softplus(x) - x*[t > k]
// B = 524288, Km1 = 64, logits fp32, targets int32, output: 1 fp32 scalar.
//
// R5/R6 history: four structural variants plateau at ~70 us backed-out
// kernel time (floor ~22 us = 136 MB @ 6.3 TB/s; VALU model ~6.5 us).
// Theory: contention with the harness's 537 MB poison-fill drain.
// Nontemporal loads (R6): NO change -> nt was not the lever.
//
// R7 (this round): test the cache-residency hypothesis. The input restore
// may transit L2/L3 (blit kernel), leaving logits L3-resident-dirty at
// kernel start. Two coupled changes:
//   (a) drop nontemporal loads (they bypass the caches -> forfeit any
//       L3 hits on the freshly-restored inputs; proven neutral on a
//       cold path, so no downside),
//   (b) REVERSE chunk traversal (highest addresses first): the L3 drains
//       oldest-written lines first, so a forward scan chases the drain
//       and always misses; a newest-first scan harvests the resident
//       portion before eviction.
// Prediction: if restore is cached, main 70 -> ~30-40 us, dur_us <= 155.
// If unchanged (+-3%), inputs are HBM-only (SDMA restore) and the drain
// contention is structural -> roofline.

#define BLOCK 256
#define GRID 2048
#define STRIDE (GRID * BLOCK)

typedef float floatx4 __attribute__((ext_vector_type(4)));

__device__ __forceinline__ float bce4(const floatx4 x4, const int c) {
    const float LOG2E = 1.44269504088896f;
    const float LN2   = 0.69314718055995f;
    float s = 0.0f;
    #pragma unroll
    for (int j = 0; j < 4; ++j) {
        const float x = x4[j];
        // log1p(exp(-|x|)) = ln2 * log2(1 + exp2(-|x|*log2e)) via hw trans ops
        const float e  = __builtin_amdgcn_exp2f(-fabsf(x) * LOG2E);
        const float lg = __builtin_amdgcn_logf(1.0f + e);
        // max(x,0) - x*[c > j] == (c > j) ? max(-x,0) : max(x,0)
        const float m  = fmaxf((c > j) ? -x : x, 0.0f);
        s += fmaf(LN2, lg, m);
    }
    return s;
}

__device__ __forceinline__ float block_reduce(float acc, float* wave_sums) {
    #pragma unroll
    for (int off = 32; off > 0; off >>= 1)
        acc += __shfl_down(acc, off, 64);
    const int lane = threadIdx.x & 63;
    const int wid = threadIdx.x >> 6;
    if (lane == 0) wave_sums[wid] = acc;
    __syncthreads();
    float s = 0.0f;
    if (threadIdx.x == 0) {
        #pragma unroll
        for (int w = 0; w < BLOCK / 64; ++w) s += wave_sums[w];
    }
    return s;
}

__global__ __launch_bounds__(BLOCK) void coral_loss_main(
    const float* __restrict__ logits,
    const int* __restrict__ targets,
    float* __restrict__ partials,   // GRID floats in d_ws
    int n_vec4,                     // B*Km1/4
    float inv_count)                // 1/(B*Km1)
{
    const floatx4* __restrict__ L4 = reinterpret_cast<const floatx4*>(logits);
    const int tid = blockIdx.x * BLOCK + threadIdx.x;
    float a0 = 0.0f, a1 = 0.0f, a2 = 0.0f, a3 = 0.0f;

    const int nfull = n_vec4 / STRIDE;   // full chunks of STRIDE vec4s

    // Partial top chunk first (highest addresses = most recently restored).
    {
        const int idx = nfull * STRIDE + tid;
        if (idx < n_vec4)
            a0 += bce4(L4[idx], targets[idx >> 4] - ((idx & 15) << 2));
    }

    // Full chunks, 4 at a time, descending through the address space.
    int c = nfull - 4;
    for (; c >= 0; c -= 4) {
        const int i3 = (c + 3) * STRIDE + tid;   // highest of the group first
        const int i2 = (c + 2) * STRIDE + tid;
        const int i1 = (c + 1) * STRIDE + tid;
        const int i0 = c * STRIDE + tid;
        const floatx4 x3 = L4[i3];
        const floatx4 x2 = L4[i2];
        const floatx4 x1 = L4[i1];
        const floatx4 x0 = L4[i0];
        const int c3 = targets[i3 >> 4] - ((i3 & 15) << 2);
        const int c2 = targets[i2 >> 4] - ((i2 & 15) << 2);
        const int c1 = targets[i1 >> 4] - ((i1 & 15) << 2);
        const int c0 = targets[i0 >> 4] - ((i0 & 15) << 2);
        a3 += bce4(x3, c3);
        a2 += bce4(x2, c2);
        a1 += bce4(x1, c1);
        a0 += bce4(x0, c0);
    }

    // Leftover full chunks at the bottom (nfull % 4), still descending.
    for (int cc = c + 3; cc >= 0; --cc) {
        const int idx = cc * STRIDE + tid;
        a0 += bce4(L4[idx], targets[idx >> 4] - ((idx & 15) << 2));
    }

    float acc = ((a0 + a1) + (a2 + a3)) * inv_count;

    __shared__ float wave_sums[BLOCK / 64];
    const float s = block_reduce(acc, wave_sums);
    if (threadIdx.x == 0) partials[blockIdx.x] = s;   // plain store, no atomic
}

__global__ __launch_bounds__(BLOCK) void coral_loss_finish(
    const float* __restrict__ partials,
    float* __restrict__ out,
    int n_partials)
{
    float acc = 0.0f;
    for (int i = threadIdx.x; i < n_partials; i += BLOCK)
        acc += partials[i];
    __shared__ float wave_sums[BLOCK / 64];
    const float s = block_reduce(acc, wave_sums);
    if (threadIdx.x == 0) out[0] = s;
}

extern "C" void kernel_launch(void* const* d_in, const int* in_sizes, int n_in,
                              void* d_out, int out_size, void* d_ws, size_t ws_size,
                              hipStream_t stream) {
    const float* logits = (const float*)d_in[0];
    const int* targets = (const int*)d_in[1];
    float* out = (float*)d_out;
    float* partials = (float*)d_ws;

    const int n_logits = in_sizes[0];       // B * Km1
    const int n_vec4 = n_logits / 4;
    const float inv_count = 1.0f / (float)n_logits;

    coral_loss_main<<<GRID, BLOCK, 0, stream>>>(
        logits, targets, partials, n_vec4, inv_count);
    coral_loss_finish<<<1, BLOCK, 0, stream>>>(partials, out, GRID);
}

// Round 2
// 184.328 us; speedup vs baseline: 1.0651x; 1.0651x over previous
//
#include <hip/hip_runtime.h>
#include <math.h>

// CoralLossV2: mean over (B, Km1) of
//   max(x,0) - x*[t > k] + log1p(exp(-|x|))  ==  softplus(x) - x*[t > k]
// B = 524288, Km1 = 64, logits fp32, targets int32, output: 1 fp32 scalar.
//
// R5/R6 history: four structural variants plateau at ~70 us backed-out
// kernel time (floor ~22 us = 136 MB @ 6.3 TB/s; VALU model ~6.5 us).
// Cause: the timed window carries the harness's 537 MB poison fill
// (77 us @ 86% peak HBM, the top-5 dispatches are all fills) + 134 MB
// input restore; our kernel starts with L3 full of dirty poison, so its
// reads contend with a ~256 MB dirty-victim drain: 134+256 MB @ 6.3 TB/s
// ~= 62 us -- matching the observed ~70 us.
// R6: nontemporal vs plain loads -> neutral.
// R7: reverse chunk traversal + cached loads -> REGRESSED 183.5 -> 196.3.
//     Inputs are not harvestably cache-resident; descending 8 MB strides
//     also fight the controller's ascending-stream behavior.
// R8 (this): exact revert to the proven-best R0 configuration (forward
// traversal, nt loads). Prediction: dur_us ~183 +- 3. That figure is the
// structural harness-traffic roofline.

#define BLOCK 256
#define GRID 2048
#define STRIDE (GRID * BLOCK)

typedef float floatx4 __attribute__((ext_vector_type(4)));

__device__ __forceinline__ float bce4(const floatx4 x4, const int c) {
    const float LOG2E = 1.44269504088896f;
    const float LN2   = 0.69314718055995f;
    float s = 0.0f;
    #pragma unroll
    for (int j = 0; j < 4; ++j) {
        const float x = x4[j];
        // log1p(exp(-|x|)) = ln2 * log2(1 + exp2(-|x|*log2e)) via hw trans ops
        const float e  = __builtin_amdgcn_exp2f(-fabsf(x) * LOG2E);
        const float lg = __builtin_amdgcn_logf(1.0f + e);
        // max(x,0) - x*[c > j] == (c > j) ? max(-x,0) : max(x,0)
        const float m  = fmaxf((c > j) ? -x : x, 0.0f);
        s += fmaf(LN2, lg, m);
    }
    return s;
}

__device__ __forceinline__ float block_reduce(float acc, float* wave_sums) {
    #pragma unroll
    for (int off = 32; off > 0; off >>= 1)
        acc += __shfl_down(acc, off, 64);
    const int lane = threadIdx.x & 63;
    const int wid = threadIdx.x >> 6;
    if (lane == 0) wave_sums[wid] = acc;
    __syncthreads();
    float s = 0.0f;
    if (threadIdx.x == 0) {
        #pragma unroll
        for (int w = 0; w < BLOCK / 64; ++w) s += wave_sums[w];
    }
    return s;
}

__global__ __launch_bounds__(BLOCK) void coral_loss_main(
    const float* __restrict__ logits,
    const int* __restrict__ targets,
    float* __restrict__ partials,   // GRID floats in d_ws
    int n_vec4,                     // B*Km1/4
    float inv_count)                // 1/(B*Km1)
{
    const floatx4* __restrict__ L4 = reinterpret_cast<const floatx4*>(logits);
    float a0 = 0.0f, a1 = 0.0f, a2 = 0.0f, a3 = 0.0f;
    int idx = blockIdx.x * BLOCK + threadIdx.x;

    for (; idx + 3 * STRIDE < n_vec4; idx += 4 * STRIDE) {
        const int i0 = idx, i1 = idx + STRIDE, i2 = idx + 2 * STRIDE, i3 = idx + 3 * STRIDE;
        const floatx4 x0 = __builtin_nontemporal_load(&L4[i0]);
        const floatx4 x1 = __builtin_nontemporal_load(&L4[i1]);
        const floatx4 x2 = __builtin_nontemporal_load(&L4[i2]);
        const floatx4 x3 = __builtin_nontemporal_load(&L4[i3]);
        const int c0 = __builtin_nontemporal_load(&targets[i0 >> 4]) - ((i0 & 15) << 2);
        const int c1 = __builtin_nontemporal_load(&targets[i1 >> 4]) - ((i1 & 15) << 2);
        const int c2 = __builtin_nontemporal_load(&targets[i2 >> 4]) - ((i2 & 15) << 2);
        const int c3 = __builtin_nontemporal_load(&targets[i3 >> 4]) - ((i3 & 15) << 2);
        a0 += bce4(x0, c0);
        a1 += bce4(x1, c1);
        a2 += bce4(x2, c2);
        a3 += bce4(x3, c3);
    }
    for (; idx < n_vec4; idx += STRIDE) {
        a0 += bce4(__builtin_nontemporal_load(&L4[idx]),
                   __builtin_nontemporal_load(&targets[idx >> 4]) - ((idx & 15) << 2));
    }

    float acc = ((a0 + a1) + (a2 + a3)) * inv_count;

    __shared__ float wave_sums[BLOCK / 64];
    const float s = block_reduce(acc, wave_sums);
    if (threadIdx.x == 0) partials[blockIdx.x] = s;   // plain store, no atomic
}

__global__ __launch_bounds__(BLOCK) void coral_loss_finish(
    const float* __restrict__ partials,
    float* __restrict__ out,
    int n_partials)
{
    float acc = 0.0f;
    for (int i = threadIdx.x; i < n_partials; i += BLOCK)
        acc += partials[i];
    __shared__ float wave_sums[BLOCK / 64];
    const float s = block_reduce(acc, wave_sums);
    if (threadIdx.x == 0) out[0] = s;
}

extern "C" void kernel_launch(void* const* d_in, const int* in_sizes, int n_in,
                              void* d_out, int out_size, void* d_ws, size_t ws_size,
                              hipStream_t stream) {
    const float* logits = (const float*)d_in[0];
    const int* targets = (const int*)d_in[1];
    float* out = (float*)d_out;
    float* partials = (float*)d_ws;

    const int n_logits = in_sizes[0];       // B * Km1
    const int n_vec4 = n_logits / 4;
    const float inv_count = 1.0f / (float)n_logits;

    coral_loss_main<<<GRID, BLOCK, 0, stream>>>(
        logits, targets, partials, n_vec4, inv_count);
    coral_loss_finish<<<1, BLOCK, 0, stream>>>(partials, out, GRID);
}